// Round 16
// baseline (386.670 us; speedup 1.0000x reference)
//
#include <hip/hip_runtime.h>

#define NTOT 200000
#define EE   1200000

typedef unsigned int u32;
typedef unsigned long long u64;
typedef __attribute__((ext_vector_type(8))) short short8v;
typedef __attribute__((ext_vector_type(4))) float f32x4;

__device__ __forceinline__ float rcpf(float x) { return __builtin_amdgcn_rcpf(x); }
__device__ __forceinline__ float sigm(float x) { return rcpf(1.f + __expf(-x)); }
__device__ __forceinline__ float tanh_f(float x) { return 1.f - 2.f * rcpf(__expf(2.f * x) + 1.f); }
__device__ __forceinline__ u32 f2bf(float f) {           // RNE f32->bf16
    u32 u = __float_as_uint(f);
    return (u + 0x7fffu + ((u >> 16) & 1u)) >> 16;
}
__device__ __forceinline__ float bf2f(u32 b) { return __uint_as_float(b << 16); }
__device__ __forceinline__ float bf_lo(u32 p) { return __uint_as_float(p << 16); }
__device__ __forceinline__ float bf_hi(u32 p) { return __uint_as_float(p & 0xffff0000u); }

__device__ __forceinline__ short8v packhi8(const float* v) {
    union { u32 u[4]; short8v s; } r;
    r.u[0] = f2bf(v[0]) | (f2bf(v[1]) << 16);
    r.u[1] = f2bf(v[2]) | (f2bf(v[3]) << 16);
    r.u[2] = f2bf(v[4]) | (f2bf(v[5]) << 16);
    r.u[3] = f2bf(v[6]) | (f2bf(v[7]) << 16);
    return r.s;
}
__device__ __forceinline__ short8v packlo8(const float* v) {
    float q[8];
    #pragma unroll
    for (int i = 0; i < 8; ++i) q[i] = v[i] - bf2f(f2bf(v[i]));
    union { u32 u[4]; short8v s; } r;
    r.u[0] = f2bf(q[0]) | (f2bf(q[1]) << 16);
    r.u[1] = f2bf(q[2]) | (f2bf(q[3]) << 16);
    r.u[2] = f2bf(q[4]) | (f2bf(q[5]) << 16);
    r.u[3] = f2bf(q[6]) | (f2bf(q[7]) << 16);
    return r.s;
}

// ---------- degree+count in ONE u64 atomic; rank captured from the returned old value ----------
__global__ __launch_bounds__(256) void k_degcnt(const float* __restrict__ ew,
                                                const int* __restrict__ dst,
                                                u64* __restrict__ pk,
                                                u32* __restrict__ rank) {
    int e = blockIdx.x*256 + threadIdx.x;
    if (e < EE) {
        u64 v = (1ull << 40) | (u64)(u32)__float2uint_rn(ew[e] * 16777216.f);
        u64 old = atomicAdd(&pk[dst[e]], v);
        rank[e] = (u32)(old >> 40);          // # earlier edges with same dst
    }
}

// scan of counts (from pk) + dinv = rsqrt(1 + fixsum*2^-24) fused
__global__ __launch_bounds__(256) void k_scan1(const u64* __restrict__ pk,
                                               int* __restrict__ off,
                                               int* __restrict__ bsum,
                                               float* __restrict__ dinv) {
    __shared__ int s[256];
    int t = threadIdx.x, i = blockIdx.x*256 + t;
    int v = 0;
    if (i < NTOT) {
        u64 p = pk[i];
        v = (int)(p >> 40);
        dinv[i] = rsqrtf(1.0f + (float)(p & 0xFFFFFFFFFFull) * 5.9604644775390625e-8f);
    }
    s[t] = v; __syncthreads();
    #pragma unroll
    for (int o = 1; o < 256; o <<= 1) {
        int a = (t >= o) ? s[t-o] : 0; __syncthreads();
        s[t] += a; __syncthreads();
    }
    if (i < NTOT) off[i] = s[t] - v;
    if (t == 255) bsum[blockIdx.x] = s[255];
}

__global__ __launch_bounds__(1024) void k_scan2(int* bsum) {   // 782 totals
    __shared__ int s[1024];
    int t = threadIdx.x;
    int v = (t < 782) ? bsum[t] : 0;
    s[t] = v; __syncthreads();
    for (int o = 1; o < 1024; o <<= 1) {
        int a = (t >= o) ? s[t-o] : 0; __syncthreads();
        s[t] += a; __syncthreads();
    }
    if (t < 782) bsum[t] = s[t] - v;
}

__global__ __launch_bounds__(256) void k_scan3(int* __restrict__ off,
                                               const int* __restrict__ bsum) {
    int i = blockIdx.x*256 + threadIdx.x;
    if (i < NTOT) off[i] = off[i] + bsum[blockIdx.x];
    if (i == 0) off[NTOT] = EE;
}

// fill CSR slots with precomputed {src, norm} — NO atomics: slot = off[dst] + rank
__global__ __launch_bounds__(256) void k_fill(const int* __restrict__ src,
                                              const int* __restrict__ dst,
                                              const float* __restrict__ ew,
                                              const float* __restrict__ dinv,
                                              const int* __restrict__ off,
                                              const u32* __restrict__ rank,
                                              uint2* __restrict__ epack) {
    int e = blockIdx.x*256 + threadIdx.x;
    if (e >= EE) return;
    int d = dst[e], s = src[e];
    float norm = dinv[s] * ew[e] * dinv[d];
    int p = off[d] + (int)rank[e];
    epack[p] = make_uint2((u32)s, __float_as_uint(norm));
}

// layer-1 scalar aggregation (T=1 rank-1 trick)
__global__ __launch_bounds__(256) void k_sagg(const int* __restrict__ off,
                                              const uint2* __restrict__ epack,
                                              const float* __restrict__ x,
                                              const float* __restrict__ dinv,
                                              float* __restrict__ sagg) {
    int n = blockIdx.x*256 + threadIdx.x;
    if (n >= NTOT) return;
    int e0 = off[n], e1 = off[n+1];
    float s = 0.f;
    for (int e = e0; e < e1; ++e) {
        uint2 ep = epack[e];
        s += __uint_as_float(ep.y) * x[ep.x];
    }
    float di = dinv[n];
    sagg[n] = s + di*di*x[n];
}

// pack wih/whh into MFMA B-frag-linear bf16: tile tau (0..23 ih, 24..47 hh)
__global__ __launch_bounds__(256) void k_wprep(const float* __restrict__ wih,
                                               const float* __restrict__ whh,
                                               uint4* __restrict__ wpack) {
    int v = blockIdx.x*256 + threadIdx.x;
    if (v >= 3072) return;
    int lane = v & 63, tau = v >> 6;
    const float* W = (tau < 24) ? wih : whh;
    int tt = tau % 24;
    int lt = tt >> 1, ks = tt & 1;
    const float* s = W + (lt*16 + (lane & 15))*64 + ks*32 + (lane >> 4)*8;
    uint4 o;
    o.x = f2bf(s[0]) | (f2bf(s[1]) << 16);
    o.y = f2bf(s[2]) | (f2bf(s[3]) << 16);
    o.z = f2bf(s[4]) | (f2bf(s[5]) << 16);
    o.w = f2bf(s[6]) | (f2bf(s[7]) << 16);
    wpack[v] = o;
}

// fused: y1 = relu(sagg*W1 + b1)  ->  A2 = y1 @ W2, stored packed bf16 (128B/row)
__global__ __launch_bounds__(256) void k_l12(const float* __restrict__ sagg,
                                             const float* __restrict__ W1,
                                             const float* __restrict__ b1,
                                             const float* __restrict__ W2,
                                             u32* __restrict__ A2p) {
    __shared__ float ysh[64][68];
    __shared__ float wsh[64*68];              // W2 row k at k*68, f32
    int t = threadIdx.x;
    int n0 = blockIdx.x * 64;
    #pragma unroll
    for (int i = 0; i < 16; ++i) {
        int v = t + i*256;                    // coalesced global read of W2
        wsh[(v >> 6)*68 + (v & 63)] = W2[v];
    }
    {
        int row = t >> 2, c0 = (t & 3) * 16;
        float sv = sagg[n0 + row];
        #pragma unroll
        for (int q = 0; q < 4; ++q) {
            float4 w  = *(const float4*)(W1 + c0 + q*4);
            float4 bb = *(const float4*)(b1 + c0 + q*4);
            ysh[row][c0+q*4+0] = fmaxf(sv*w.x + bb.x, 0.f);
            ysh[row][c0+q*4+1] = fmaxf(sv*w.y + bb.y, 0.f);
            ysh[row][c0+q*4+2] = fmaxf(sv*w.z + bb.z, 0.f);
            ysh[row][c0+q*4+3] = fmaxf(sv*w.w + bb.w, 0.f);
        }
    }
    __syncthreads();
    int p = t >> 3, c = t & 7;
    float acc0[8], acc1[8];
    #pragma unroll
    for (int j = 0; j < 8; ++j) { acc0[j] = 0.f; acc1[j] = 0.f; }
    #pragma unroll 4
    for (int k = 0; k < 64; ++k) {
        float y0 = ysh[p][k], y1 = ysh[p+32][k];
        const float* wr = wsh + k*68 + c*8;
        float4 w0 = *(const float4*)wr;
        float4 w1 = *(const float4*)(wr + 4);
        acc0[0] += y0*w0.x; acc0[1] += y0*w0.y; acc0[2] += y0*w0.z; acc0[3] += y0*w0.w;
        acc0[4] += y0*w1.x; acc0[5] += y0*w1.y; acc0[6] += y0*w1.z; acc0[7] += y0*w1.w;
        acc1[0] += y1*w0.x; acc1[1] += y1*w0.y; acc1[2] += y1*w0.z; acc1[3] += y1*w0.w;
        acc1[4] += y1*w1.x; acc1[5] += y1*w1.y; acc1[6] += y1*w1.z; acc1[7] += y1*w1.w;
    }
    int na = n0 + p, nb = n0 + p + 32;
    uint4 pk;
    pk.x = f2bf(acc0[0]) | (f2bf(acc0[1]) << 16);
    pk.y = f2bf(acc0[2]) | (f2bf(acc0[3]) << 16);
    pk.z = f2bf(acc0[4]) | (f2bf(acc0[5]) << 16);
    pk.w = f2bf(acc0[6]) | (f2bf(acc0[7]) << 16);
    *(uint4*)(A2p + (size_t)na*32 + c*4) = pk;
    pk.x = f2bf(acc1[0]) | (f2bf(acc1[1]) << 16);
    pk.y = f2bf(acc1[2]) | (f2bf(acc1[3]) << 16);
    pk.z = f2bf(acc1[4]) | (f2bf(acc1[5]) << 16);
    pk.w = f2bf(acc1[6]) | (f2bf(acc1[7]) << 16);
    *(uint4*)(A2p + (size_t)nb*32 + c*4) = pk;
}

// ---------- FUSED gather + MFMA GRU + FC head ----------
// Block = 256 thr = 4 waves, 64 nodes. Phase 1: CSR gather -> ysh (f32, pad 68).
// Phase 2: MFMA GRU identical to proven round-9 code, fragments from LDS.
__global__ __launch_bounds__(256) void k_ggru(const u32* __restrict__ A2p,
                                              const uint2* __restrict__ epack,
                                              const int* __restrict__ off,
                                              const float* __restrict__ dinv,
                                              const float* __restrict__ b2,
                                              const float* __restrict__ h_in,
                                              const uint4* __restrict__ wpack,
                                              const float* __restrict__ bih,
                                              const float* __restrict__ bhh,
                                              const float* __restrict__ fcw,
                                              const float* __restrict__ fcb,
                                              float* __restrict__ out,
                                              float* __restrict__ hnew) {
    __shared__ float ysh[64][68];             // pad 68: b128 row-strided reads = 2-way (free)
    __shared__ float hsh[64][68];
    int t = threadIdx.x;
    int lane = t & 63, w = t >> 6;
    int n0 = blockIdx.x * 64;
    {   // stage h coalesced (issued early; latency hides under gather)
        int r = t >> 2, qq = t & 3;
        const float4* hp = (const float4*)(h_in + (size_t)(n0 + r)*64 + qq*16);
        float4* dp = (float4*)&hsh[r][qq*16];
        dp[0] = hp[0]; dp[1] = hp[1]; dp[2] = hp[2]; dp[3] = hp[3];
    }
    // gather phase: wave w handles nodes w*16..w*16+15; 4 edges in flight (g), 4 cols/lane (q)
    int g = lane >> 4, q = lane & 15;
    for (int i = 0; i < 16; ++i) {
        int node = n0 + w*16 + i;
        int e0 = off[node], e1 = off[node+1];
        float ax = 0.f, ay = 0.f, az = 0.f, av = 0.f;
        for (int e = e0 + g; e < e1; e += 4) {
            uint2 ep = epack[e];
            float nrm = __uint_as_float(ep.y);
            uint2 pw = *(const uint2*)(A2p + (size_t)ep.x*32 + q*2);
            ax += nrm*bf_lo(pw.x); ay += nrm*bf_hi(pw.x);
            az += nrm*bf_lo(pw.y); av += nrm*bf_hi(pw.y);
        }
        ax += __shfl_xor(ax, 16); ax += __shfl_xor(ax, 32);
        ay += __shfl_xor(ay, 16); ay += __shfl_xor(ay, 32);
        az += __shfl_xor(az, 16); az += __shfl_xor(az, 32);
        av += __shfl_xor(av, 16); av += __shfl_xor(av, 32);
        if (g == 0) {
            float di = dinv[node], d2 = di*di;
            uint2 pw = *(const uint2*)(A2p + (size_t)node*32 + q*2);
            float4 bb = *(const float4*)(b2 + q*4);
            float4 o;
            o.x = fmaxf(ax + d2*bf_lo(pw.x) + bb.x, 0.f);
            o.y = fmaxf(ay + d2*bf_hi(pw.x) + bb.y, 0.f);
            o.z = fmaxf(az + d2*bf_lo(pw.y) + bb.z, 0.f);
            o.w = fmaxf(av + d2*bf_hi(pw.y) + bb.w, 0.f);
            *(float4*)&ysh[w*16 + i][q*4] = o;
        }
    }
    __syncthreads();
    // MFMA GRU phase (round-9 proven code; fragment sources = LDS)
    int rowL = w*16 + (lane & 15);
    int kb = (lane >> 4) * 8;
    float yf[16], hb[16];
    *(float4*)&yf[0]  = *(const float4*)&ysh[rowL][kb];
    *(float4*)&yf[4]  = *(const float4*)&ysh[rowL][kb+4];
    *(float4*)&yf[8]  = *(const float4*)&ysh[rowL][kb+32];
    *(float4*)&yf[12] = *(const float4*)&ysh[rowL][kb+36];
    *(float4*)&hb[0]  = *(const float4*)&hsh[rowL][kb];
    *(float4*)&hb[4]  = *(const float4*)&hsh[rowL][kb+4];
    *(float4*)&hb[8]  = *(const float4*)&hsh[rowL][kb+32];
    *(float4*)&hb[12] = *(const float4*)&hsh[rowL][kb+36];
    short8v ya0h = packhi8(&yf[0]), ya1h = packhi8(&yf[8]);
    short8v ya0l = packlo8(&yf[0]), ya1l = packlo8(&yf[8]);
    short8v ha0h = packhi8(&hb[0]), ha1h = packhi8(&hb[8]);
    short8v ha0l = packlo8(&hb[0]), ha1l = packlo8(&hb[8]);
    float po[4][5] = {};
    #pragma unroll
    for (int lt = 0; lt < 4; ++lt) {
        short8v wbr0 = *(const short8v*)&wpack[(lt*2+0)*64 + lane];
        short8v wbr1 = *(const short8v*)&wpack[(lt*2+1)*64 + lane];
        short8v wbz0 = *(const short8v*)&wpack[((lt+4)*2+0)*64 + lane];
        short8v wbz1 = *(const short8v*)&wpack[((lt+4)*2+1)*64 + lane];
        short8v wbn0 = *(const short8v*)&wpack[((lt+8)*2+0)*64 + lane];
        short8v wbn1 = *(const short8v*)&wpack[((lt+8)*2+1)*64 + lane];
        short8v vbr0 = *(const short8v*)&wpack[1536 + (lt*2+0)*64 + lane];
        short8v vbr1 = *(const short8v*)&wpack[1536 + (lt*2+1)*64 + lane];
        short8v vbz0 = *(const short8v*)&wpack[1536 + ((lt+4)*2+0)*64 + lane];
        short8v vbz1 = *(const short8v*)&wpack[1536 + ((lt+4)*2+1)*64 + lane];
        short8v vbn0 = *(const short8v*)&wpack[1536 + ((lt+8)*2+0)*64 + lane];
        short8v vbn1 = *(const short8v*)&wpack[1536 + ((lt+8)*2+1)*64 + lane];
        f32x4 aR  = {0.f,0.f,0.f,0.f};
        f32x4 aZ  = {0.f,0.f,0.f,0.f};
        f32x4 aNi = {0.f,0.f,0.f,0.f};
        f32x4 aNh = {0.f,0.f,0.f,0.f};
        aR = __builtin_amdgcn_mfma_f32_16x16x32_bf16(ya0h, wbr0, aR, 0, 0, 0);
        aR = __builtin_amdgcn_mfma_f32_16x16x32_bf16(ya1h, wbr1, aR, 0, 0, 0);
        aR = __builtin_amdgcn_mfma_f32_16x16x32_bf16(ya0l, wbr0, aR, 0, 0, 0);
        aR = __builtin_amdgcn_mfma_f32_16x16x32_bf16(ya1l, wbr1, aR, 0, 0, 0);
        aR = __builtin_amdgcn_mfma_f32_16x16x32_bf16(ha0h, vbr0, aR, 0, 0, 0);
        aR = __builtin_amdgcn_mfma_f32_16x16x32_bf16(ha1h, vbr1, aR, 0, 0, 0);
        aR = __builtin_amdgcn_mfma_f32_16x16x32_bf16(ha0l, vbr0, aR, 0, 0, 0);
        aR = __builtin_amdgcn_mfma_f32_16x16x32_bf16(ha1l, vbr1, aR, 0, 0, 0);
        aZ = __builtin_amdgcn_mfma_f32_16x16x32_bf16(ya0h, wbz0, aZ, 0, 0, 0);
        aZ = __builtin_amdgcn_mfma_f32_16x16x32_bf16(ya1h, wbz1, aZ, 0, 0, 0);
        aZ = __builtin_amdgcn_mfma_f32_16x16x32_bf16(ya0l, wbz0, aZ, 0, 0, 0);
        aZ = __builtin_amdgcn_mfma_f32_16x16x32_bf16(ya1l, wbz1, aZ, 0, 0, 0);
        aZ = __builtin_amdgcn_mfma_f32_16x16x32_bf16(ha0h, vbz0, aZ, 0, 0, 0);
        aZ = __builtin_amdgcn_mfma_f32_16x16x32_bf16(ha1h, vbz1, aZ, 0, 0, 0);
        aZ = __builtin_amdgcn_mfma_f32_16x16x32_bf16(ha0l, vbz0, aZ, 0, 0, 0);
        aZ = __builtin_amdgcn_mfma_f32_16x16x32_bf16(ha1l, vbz1, aZ, 0, 0, 0);
        aNi = __builtin_amdgcn_mfma_f32_16x16x32_bf16(ya0h, wbn0, aNi, 0, 0, 0);
        aNi = __builtin_amdgcn_mfma_f32_16x16x32_bf16(ya1h, wbn1, aNi, 0, 0, 0);
        aNi = __builtin_amdgcn_mfma_f32_16x16x32_bf16(ya0l, wbn0, aNi, 0, 0, 0);
        aNi = __builtin_amdgcn_mfma_f32_16x16x32_bf16(ya1l, wbn1, aNi, 0, 0, 0);
        aNh = __builtin_amdgcn_mfma_f32_16x16x32_bf16(ha0h, vbn0, aNh, 0, 0, 0);
        aNh = __builtin_amdgcn_mfma_f32_16x16x32_bf16(ha1h, vbn1, aNh, 0, 0, 0);
        aNh = __builtin_amdgcn_mfma_f32_16x16x32_bf16(ha0l, vbn0, aNh, 0, 0, 0);
        aNh = __builtin_amdgcn_mfma_f32_16x16x32_bf16(ha1l, vbn1, aNh, 0, 0, 0);
        int l = lt*16 + (lane & 15);
        float br = bih[l] + bhh[l];
        float bz = bih[64+l] + bhh[64+l];
        float bn = bih[128+l];
        float cn = bhh[128+l];
        float fw0 = fcw[l*5+0], fw1 = fcw[l*5+1], fw2 = fcw[l*5+2],
              fw3 = fcw[l*5+3], fw4 = fcw[l*5+4];
        #pragma unroll
        for (int r4 = 0; r4 < 4; ++r4) {
            int rl = w*16 + (lane >> 4)*4 + r4;      // local row in block
            float rg = sigm(aR[r4] + br);
            float zg = sigm(aZ[r4] + bz);
            float ng = tanh_f(aNi[r4] + bn + rg*(aNh[r4] + cn));
            float hfv = hsh[rl][l];
            float hnv = (1.f - zg)*ng + zg*hfv;
            hnew[(size_t)(n0 + rl)*64 + l] = hnv;
            po[r4][0] += hnv*fw0; po[r4][1] += hnv*fw1; po[r4][2] += hnv*fw2;
            po[r4][3] += hnv*fw3; po[r4][4] += hnv*fw4;
        }
    }
    #pragma unroll
    for (int r4 = 0; r4 < 4; ++r4)
        #pragma unroll
        for (int j = 0; j < 5; ++j) {
            float v = po[r4][j];
            v += __shfl_xor(v, 1); v += __shfl_xor(v, 2);
            v += __shfl_xor(v, 4); v += __shfl_xor(v, 8);
            po[r4][j] = v;
        }
    if ((lane & 15) == 0) {
        #pragma unroll
        for (int r4 = 0; r4 < 4; ++r4) {
            int node = n0 + w*16 + (lane >> 4)*4 + r4;
            #pragma unroll
            for (int j = 0; j < 5; ++j) out[(size_t)node*5 + j] = po[r4][j] + fcb[j];
        }
    }
}

extern "C" void kernel_launch(void* const* d_in, const int* in_sizes, int n_in,
                              void* d_out, int out_size, void* d_ws, size_t ws_size,
                              hipStream_t stream) {
    const float* x   = (const float*)d_in[0];
    const float* ew  = (const float*)d_in[1];
    const float* h   = (const float*)d_in[2];
    const float* W1  = (const float*)d_in[3];
    const float* b1  = (const float*)d_in[4];
    const float* W2  = (const float*)d_in[5];
    const float* b2  = (const float*)d_in[6];
    const float* wih = (const float*)d_in[7];
    const float* whh = (const float*)d_in[8];
    const float* bih = (const float*)d_in[9];
    const float* bhh = (const float*)d_in[10];
    const float* fcw = (const float*)d_in[11];
    const float* fcb = (const float*)d_in[12];
    const int*   ei  = (const int*)d_in[13];
    const int* src = ei;
    const int* dst = ei + EE;

    // ws: A2p @0 (25.6MB) | epack @25.6M (9.6MB) | wpack @35.2M (48KB) | pk @36M (1.6MB)
    //     | rank @38M (4.8MB) | off @43M | bsum @44M | dinv @45M | sagg @46M
    // NOTE: all CSR metadata now in ws — k_ggru reads off/dinv while writing d_out (no alias).
    u32*   A2p   = (u32*)d_ws;
    uint2* epack = (uint2*)((char*)d_ws + 25600000);
    uint4* wpack = (uint4*)((char*)d_ws + 35200000);
    u64*   pk    = (u64*)((char*)d_ws + 36000000);
    u32*   rank  = (u32*)((char*)d_ws + 38000000);
    int*   off   = (int*)((char*)d_ws + 43000000);    // NTOT+1
    int*   bsum  = (int*)((char*)d_ws + 44000000);    // 782
    float* dinv  = (float*)((char*)d_ws + 45000000);
    float* sagg  = (float*)((char*)d_ws + 46000000);
    float* out  = (float*)d_out;
    float* hnew = out + (size_t)NTOT*5;               // d_out tail

    hipMemsetAsync(pk, 0, (size_t)NTOT*8, stream);
    k_degcnt<<<4688, 256, 0, stream>>>(ew, dst, pk, rank);
    k_scan1 <<<782,  256, 0, stream>>>(pk, off, bsum, dinv);
    k_scan2 <<<1,   1024, 0, stream>>>(bsum);
    k_scan3 <<<782,  256, 0, stream>>>(off, bsum);
    k_fill  <<<4688, 256, 0, stream>>>(src, dst, ew, dinv, off, rank, epack);
    k_sagg  <<<782,  256, 0, stream>>>(off, epack, x, dinv, sagg);
    k_wprep <<<12,   256, 0, stream>>>(wih, whh, wpack);
    k_l12   <<<3125, 256, 0, stream>>>(sagg, W1, b1, W2, A2p);
    k_ggru  <<<3125, 256, 0, stream>>>(A2p, epack, off, dinv, b2, h, wpack,
                                       bih, bhh, fcw, fcb, out, hnew);
}

// Round 17
// 267.196 us; speedup vs baseline: 1.4471x; 1.4471x over previous
//
#include <hip/hip_runtime.h>

#define NTOT 200000
#define EE   1200000

typedef unsigned int u32;
typedef unsigned long long u64;
typedef __attribute__((ext_vector_type(8))) short short8v;
typedef __attribute__((ext_vector_type(4))) float f32x4;

__device__ __forceinline__ float rcpf(float x) { return __builtin_amdgcn_rcpf(x); }
__device__ __forceinline__ float sigm(float x) { return rcpf(1.f + __expf(-x)); }
__device__ __forceinline__ float tanh_f(float x) { return 1.f - 2.f * rcpf(__expf(2.f * x) + 1.f); }
__device__ __forceinline__ u32 f2bf(float f) {           // RNE f32->bf16
    u32 u = __float_as_uint(f);
    return (u + 0x7fffu + ((u >> 16) & 1u)) >> 16;
}
__device__ __forceinline__ float bf2f(u32 b) { return __uint_as_float(b << 16); }
__device__ __forceinline__ float bf_lo(u32 p) { return __uint_as_float(p << 16); }
__device__ __forceinline__ float bf_hi(u32 p) { return __uint_as_float(p & 0xffff0000u); }

__device__ __forceinline__ short8v packhi8(const float* v) {
    union { u32 u[4]; short8v s; } r;
    r.u[0] = f2bf(v[0]) | (f2bf(v[1]) << 16);
    r.u[1] = f2bf(v[2]) | (f2bf(v[3]) << 16);
    r.u[2] = f2bf(v[4]) | (f2bf(v[5]) << 16);
    r.u[3] = f2bf(v[6]) | (f2bf(v[7]) << 16);
    return r.s;
}
__device__ __forceinline__ short8v packlo8(const float* v) {
    float q[8];
    #pragma unroll
    for (int i = 0; i < 8; ++i) q[i] = v[i] - bf2f(f2bf(v[i]));
    union { u32 u[4]; short8v s; } r;
    r.u[0] = f2bf(q[0]) | (f2bf(q[1]) << 16);
    r.u[1] = f2bf(q[2]) | (f2bf(q[3]) << 16);
    r.u[2] = f2bf(q[4]) | (f2bf(q[5]) << 16);
    r.u[3] = f2bf(q[6]) | (f2bf(q[7]) << 16);
    return r.s;
}

// ---------- degree+count in ONE u64 atomic; rank captured from the returned old value ----------
__global__ __launch_bounds__(256) void k_degcnt(const float* __restrict__ ew,
                                                const int* __restrict__ dst,
                                                u64* __restrict__ pk,
                                                u32* __restrict__ rank) {
    int e = blockIdx.x*256 + threadIdx.x;
    if (e < EE) {
        u64 v = (1ull << 40) | (u64)(u32)__float2uint_rn(ew[e] * 16777216.f);
        u64 old = atomicAdd(&pk[dst[e]], v);
        rank[e] = (u32)(old >> 40);          // # earlier edges with same dst
    }
}

// scan of counts (from pk) + dinv = rsqrt(1 + fixsum*2^-24) fused
__global__ __launch_bounds__(256) void k_scan1(const u64* __restrict__ pk,
                                               int* __restrict__ off,
                                               int* __restrict__ bsum,
                                               float* __restrict__ dinv) {
    __shared__ int s[256];
    int t = threadIdx.x, i = blockIdx.x*256 + t;
    int v = 0;
    if (i < NTOT) {
        u64 p = pk[i];
        v = (int)(p >> 40);
        dinv[i] = rsqrtf(1.0f + (float)(p & 0xFFFFFFFFFFull) * 5.9604644775390625e-8f);
    }
    s[t] = v; __syncthreads();
    #pragma unroll
    for (int o = 1; o < 256; o <<= 1) {
        int a = (t >= o) ? s[t-o] : 0; __syncthreads();
        s[t] += a; __syncthreads();
    }
    if (i < NTOT) off[i] = s[t] - v;
    if (t == 255) bsum[blockIdx.x] = s[255];
}

__global__ __launch_bounds__(1024) void k_scan2(int* bsum) {   // 782 totals
    __shared__ int s[1024];
    int t = threadIdx.x;
    int v = (t < 782) ? bsum[t] : 0;
    s[t] = v; __syncthreads();
    for (int o = 1; o < 1024; o <<= 1) {
        int a = (t >= o) ? s[t-o] : 0; __syncthreads();
        s[t] += a; __syncthreads();
    }
    if (t < 782) bsum[t] = s[t] - v;
}

__global__ __launch_bounds__(256) void k_scan3(int* __restrict__ off,
                                               const int* __restrict__ bsum) {
    int i = blockIdx.x*256 + threadIdx.x;
    if (i < NTOT) off[i] = off[i] + bsum[blockIdx.x];
    if (i == 0) off[NTOT] = EE;
}

// fill CSR slots with precomputed {src, norm} — NO atomics: slot = off[dst] + rank
__global__ __launch_bounds__(256) void k_fill(const int* __restrict__ src,
                                              const int* __restrict__ dst,
                                              const float* __restrict__ ew,
                                              const float* __restrict__ dinv,
                                              const int* __restrict__ off,
                                              const u32* __restrict__ rank,
                                              uint2* __restrict__ epack) {
    int e = blockIdx.x*256 + threadIdx.x;
    if (e >= EE) return;
    int d = dst[e], s = src[e];
    float norm = dinv[s] * ew[e] * dinv[d];
    int p = off[d] + (int)rank[e];
    epack[p] = make_uint2((u32)s, __float_as_uint(norm));
}

// layer-1 scalar aggregation (T=1 rank-1 trick)
__global__ __launch_bounds__(256) void k_sagg(const int* __restrict__ off,
                                              const uint2* __restrict__ epack,
                                              const float* __restrict__ x,
                                              const float* __restrict__ dinv,
                                              float* __restrict__ sagg) {
    int n = blockIdx.x*256 + threadIdx.x;
    if (n >= NTOT) return;
    int e0 = off[n], e1 = off[n+1];
    float s = 0.f;
    for (int e = e0; e < e1; ++e) {
        uint2 ep = epack[e];
        s += __uint_as_float(ep.y) * x[ep.x];
    }
    float di = dinv[n];
    sagg[n] = s + di*di*x[n];
}

// pack wih/whh into MFMA B-frag-linear bf16: tile tau (0..23 ih, 24..47 hh)
__global__ __launch_bounds__(256) void k_wprep(const float* __restrict__ wih,
                                               const float* __restrict__ whh,
                                               uint4* __restrict__ wpack) {
    int v = blockIdx.x*256 + threadIdx.x;
    if (v >= 3072) return;
    int lane = v & 63, tau = v >> 6;
    const float* W = (tau < 24) ? wih : whh;
    int tt = tau % 24;
    int lt = tt >> 1, ks = tt & 1;
    const float* s = W + (lt*16 + (lane & 15))*64 + ks*32 + (lane >> 4)*8;
    uint4 o;
    o.x = f2bf(s[0]) | (f2bf(s[1]) << 16);
    o.y = f2bf(s[2]) | (f2bf(s[3]) << 16);
    o.z = f2bf(s[4]) | (f2bf(s[5]) << 16);
    o.w = f2bf(s[6]) | (f2bf(s[7]) << 16);
    wpack[v] = o;
}

// fused: y1 = relu(sagg*W1 + b1)  ->  A2 = y1 @ W2, stored packed bf16 (128B/row)
__global__ __launch_bounds__(256) void k_l12(const float* __restrict__ sagg,
                                             const float* __restrict__ W1,
                                             const float* __restrict__ b1,
                                             const float* __restrict__ W2,
                                             u32* __restrict__ A2p) {
    __shared__ float ysh[64][68];
    __shared__ float wsh[64*68];              // W2 row k at k*68, f32
    int t = threadIdx.x;
    int n0 = blockIdx.x * 64;
    #pragma unroll
    for (int i = 0; i < 16; ++i) {
        int v = t + i*256;                    // coalesced global read of W2
        wsh[(v >> 6)*68 + (v & 63)] = W2[v];
    }
    {
        int row = t >> 2, c0 = (t & 3) * 16;
        float sv = sagg[n0 + row];
        #pragma unroll
        for (int q = 0; q < 4; ++q) {
            float4 w  = *(const float4*)(W1 + c0 + q*4);
            float4 bb = *(const float4*)(b1 + c0 + q*4);
            ysh[row][c0+q*4+0] = fmaxf(sv*w.x + bb.x, 0.f);
            ysh[row][c0+q*4+1] = fmaxf(sv*w.y + bb.y, 0.f);
            ysh[row][c0+q*4+2] = fmaxf(sv*w.z + bb.z, 0.f);
            ysh[row][c0+q*4+3] = fmaxf(sv*w.w + bb.w, 0.f);
        }
    }
    __syncthreads();
    int p = t >> 3, c = t & 7;
    float acc0[8], acc1[8];
    #pragma unroll
    for (int j = 0; j < 8; ++j) { acc0[j] = 0.f; acc1[j] = 0.f; }
    #pragma unroll 4
    for (int k = 0; k < 64; ++k) {
        float y0 = ysh[p][k], y1 = ysh[p+32][k];
        const float* wr = wsh + k*68 + c*8;
        float4 w0 = *(const float4*)wr;
        float4 w1 = *(const float4*)(wr + 4);
        acc0[0] += y0*w0.x; acc0[1] += y0*w0.y; acc0[2] += y0*w0.z; acc0[3] += y0*w0.w;
        acc0[4] += y0*w1.x; acc0[5] += y0*w1.y; acc0[6] += y0*w1.z; acc0[7] += y0*w1.w;
        acc1[0] += y1*w0.x; acc1[1] += y1*w0.y; acc1[2] += y1*w0.z; acc1[3] += y1*w0.w;
        acc1[4] += y1*w1.x; acc1[5] += y1*w1.y; acc1[6] += y1*w1.z; acc1[7] += y1*w1.w;
    }
    int na = n0 + p, nb = n0 + p + 32;
    uint4 pk;
    pk.x = f2bf(acc0[0]) | (f2bf(acc0[1]) << 16);
    pk.y = f2bf(acc0[2]) | (f2bf(acc0[3]) << 16);
    pk.z = f2bf(acc0[4]) | (f2bf(acc0[5]) << 16);
    pk.w = f2bf(acc0[6]) | (f2bf(acc0[7]) << 16);
    *(uint4*)(A2p + (size_t)na*32 + c*4) = pk;
    pk.x = f2bf(acc1[0]) | (f2bf(acc1[1]) << 16);
    pk.y = f2bf(acc1[2]) | (f2bf(acc1[3]) << 16);
    pk.z = f2bf(acc1[4]) | (f2bf(acc1[5]) << 16);
    pk.w = f2bf(acc1[6]) | (f2bf(acc1[7]) << 16);
    *(uint4*)(A2p + (size_t)nb*32 + c*4) = pk;
}

// CSR gather, 4-edge ILP, bf16 rows  (round-12 proven: wave per node, 200K waves of TLP)
__global__ __launch_bounds__(256) void k_gather(const u32* __restrict__ A2p,
                                                const uint2* __restrict__ epack,
                                                const int* __restrict__ off,
                                                const float* __restrict__ dinv,
                                                const float* __restrict__ b2,
                                                float* __restrict__ B2) {
    int wv = (blockIdx.x*256 + threadIdx.x) >> 6;
    int lane = threadIdx.x & 63;
    if (wv >= NTOT) return;
    int g = lane >> 4, q = lane & 15;
    int e0 = off[wv], e1 = off[wv+1];
    float ax = 0.f, ay = 0.f, az = 0.f, aw = 0.f;
    for (int e = e0 + g; e < e1; e += 4) {
        uint2 ep = epack[e];
        int sr = (int)ep.x;
        float nrm = __uint_as_float(ep.y);
        uint2 pw = *(const uint2*)(A2p + (size_t)sr*32 + q*2);
        ax += nrm*bf_lo(pw.x); ay += nrm*bf_hi(pw.x);
        az += nrm*bf_lo(pw.y); aw += nrm*bf_hi(pw.y);
    }
    ax += __shfl_xor(ax, 16); ax += __shfl_xor(ax, 32);
    ay += __shfl_xor(ay, 16); ay += __shfl_xor(ay, 32);
    az += __shfl_xor(az, 16); az += __shfl_xor(az, 32);
    aw += __shfl_xor(aw, 16); aw += __shfl_xor(aw, 32);
    if (g == 0) {
        float di = dinv[wv], d2 = di*di;
        uint2 pw = *(const uint2*)(A2p + (size_t)wv*32 + q*2);
        float4 bb = *(const float4*)(b2 + q*4);
        float4 o;
        o.x = fmaxf(ax + d2*bf_lo(pw.x) + bb.x, 0.f);
        o.y = fmaxf(ay + d2*bf_hi(pw.x) + bb.y, 0.f);
        o.z = fmaxf(az + d2*bf_lo(pw.y) + bb.z, 0.f);
        o.w = fmaxf(aw + d2*bf_hi(pw.y) + bb.w, 0.f);
        *(float4*)(B2 + (size_t)wv*64 + q*4) = o;
    }
}

// ---------- MFMA GRU + FC head, LDS-staged (k_ggru's validated MFMA phase, standalone) ----------
__global__ __launch_bounds__(256) void k_gru(const float* B2,
                                             const float* __restrict__ h_in,
                                             const uint4* __restrict__ wpack,
                                             const float* __restrict__ bih,
                                             const float* __restrict__ bhh,
                                             const float* __restrict__ fcw,
                                             const float* __restrict__ fcb,
                                             float* __restrict__ out,
                                             float* hnew) {
    __shared__ float ysh[64][68];             // pad 68: b128 row-strided reads = 2-way (free)
    __shared__ float hsh[64][68];
    int t = threadIdx.x;
    int lane = t & 63, w = t >> 6;
    int n0 = blockIdx.x * 64;
    {   // coalesced staging of B2 and h tiles
        int r = t >> 2, qq = t & 3;
        const float4* bp = (const float4*)(B2 + (size_t)(n0 + r)*64 + qq*16);
        const float4* hp = (const float4*)(h_in + (size_t)(n0 + r)*64 + qq*16);
        float4* dy = (float4*)&ysh[r][qq*16];
        float4* dh = (float4*)&hsh[r][qq*16];
        dy[0] = bp[0]; dy[1] = bp[1]; dy[2] = bp[2]; dy[3] = bp[3];
        dh[0] = hp[0]; dh[1] = hp[1]; dh[2] = hp[2]; dh[3] = hp[3];
    }
    __syncthreads();
    int rowL = w*16 + (lane & 15);
    int kb = (lane >> 4) * 8;
    float yf[16], hb[16];
    *(float4*)&yf[0]  = *(const float4*)&ysh[rowL][kb];
    *(float4*)&yf[4]  = *(const float4*)&ysh[rowL][kb+4];
    *(float4*)&yf[8]  = *(const float4*)&ysh[rowL][kb+32];
    *(float4*)&yf[12] = *(const float4*)&ysh[rowL][kb+36];
    *(float4*)&hb[0]  = *(const float4*)&hsh[rowL][kb];
    *(float4*)&hb[4]  = *(const float4*)&hsh[rowL][kb+4];
    *(float4*)&hb[8]  = *(const float4*)&hsh[rowL][kb+32];
    *(float4*)&hb[12] = *(const float4*)&hsh[rowL][kb+36];
    short8v ya0h = packhi8(&yf[0]), ya1h = packhi8(&yf[8]);
    short8v ya0l = packlo8(&yf[0]), ya1l = packlo8(&yf[8]);
    short8v ha0h = packhi8(&hb[0]), ha1h = packhi8(&hb[8]);
    short8v ha0l = packlo8(&hb[0]), ha1l = packlo8(&hb[8]);
    float po[4][5] = {};
    #pragma unroll
    for (int lt = 0; lt < 4; ++lt) {
        short8v wbr0 = *(const short8v*)&wpack[(lt*2+0)*64 + lane];
        short8v wbr1 = *(const short8v*)&wpack[(lt*2+1)*64 + lane];
        short8v wbz0 = *(const short8v*)&wpack[((lt+4)*2+0)*64 + lane];
        short8v wbz1 = *(const short8v*)&wpack[((lt+4)*2+1)*64 + lane];
        short8v wbn0 = *(const short8v*)&wpack[((lt+8)*2+0)*64 + lane];
        short8v wbn1 = *(const short8v*)&wpack[((lt+8)*2+1)*64 + lane];
        short8v vbr0 = *(const short8v*)&wpack[1536 + (lt*2+0)*64 + lane];
        short8v vbr1 = *(const short8v*)&wpack[1536 + (lt*2+1)*64 + lane];
        short8v vbz0 = *(const short8v*)&wpack[1536 + ((lt+4)*2+0)*64 + lane];
        short8v vbz1 = *(const short8v*)&wpack[1536 + ((lt+4)*2+1)*64 + lane];
        short8v vbn0 = *(const short8v*)&wpack[1536 + ((lt+8)*2+0)*64 + lane];
        short8v vbn1 = *(const short8v*)&wpack[1536 + ((lt+8)*2+1)*64 + lane];
        f32x4 aR  = {0.f,0.f,0.f,0.f};
        f32x4 aZ  = {0.f,0.f,0.f,0.f};
        f32x4 aNi = {0.f,0.f,0.f,0.f};
        f32x4 aNh = {0.f,0.f,0.f,0.f};
        aR = __builtin_amdgcn_mfma_f32_16x16x32_bf16(ya0h, wbr0, aR, 0, 0, 0);
        aR = __builtin_amdgcn_mfma_f32_16x16x32_bf16(ya1h, wbr1, aR, 0, 0, 0);
        aR = __builtin_amdgcn_mfma_f32_16x16x32_bf16(ya0l, wbr0, aR, 0, 0, 0);
        aR = __builtin_amdgcn_mfma_f32_16x16x32_bf16(ya1l, wbr1, aR, 0, 0, 0);
        aR = __builtin_amdgcn_mfma_f32_16x16x32_bf16(ha0h, vbr0, aR, 0, 0, 0);
        aR = __builtin_amdgcn_mfma_f32_16x16x32_bf16(ha1h, vbr1, aR, 0, 0, 0);
        aR = __builtin_amdgcn_mfma_f32_16x16x32_bf16(ha0l, vbr0, aR, 0, 0, 0);
        aR = __builtin_amdgcn_mfma_f32_16x16x32_bf16(ha1l, vbr1, aR, 0, 0, 0);
        aZ = __builtin_amdgcn_mfma_f32_16x16x32_bf16(ya0h, wbz0, aZ, 0, 0, 0);
        aZ = __builtin_amdgcn_mfma_f32_16x16x32_bf16(ya1h, wbz1, aZ, 0, 0, 0);
        aZ = __builtin_amdgcn_mfma_f32_16x16x32_bf16(ya0l, wbz0, aZ, 0, 0, 0);
        aZ = __builtin_amdgcn_mfma_f32_16x16x32_bf16(ya1l, wbz1, aZ, 0, 0, 0);
        aZ = __builtin_amdgcn_mfma_f32_16x16x32_bf16(ha0h, vbz0, aZ, 0, 0, 0);
        aZ = __builtin_amdgcn_mfma_f32_16x16x32_bf16(ha1h, vbz1, aZ, 0, 0, 0);
        aZ = __builtin_amdgcn_mfma_f32_16x16x32_bf16(ha0l, vbz0, aZ, 0, 0, 0);
        aZ = __builtin_amdgcn_mfma_f32_16x16x32_bf16(ha1l, vbz1, aZ, 0, 0, 0);
        aNi = __builtin_amdgcn_mfma_f32_16x16x32_bf16(ya0h, wbn0, aNi, 0, 0, 0);
        aNi = __builtin_amdgcn_mfma_f32_16x16x32_bf16(ya1h, wbn1, aNi, 0, 0, 0);
        aNi = __builtin_amdgcn_mfma_f32_16x16x32_bf16(ya0l, wbn0, aNi, 0, 0, 0);
        aNi = __builtin_amdgcn_mfma_f32_16x16x32_bf16(ya1l, wbn1, aNi, 0, 0, 0);
        aNh = __builtin_amdgcn_mfma_f32_16x16x32_bf16(ha0h, vbn0, aNh, 0, 0, 0);
        aNh = __builtin_amdgcn_mfma_f32_16x16x32_bf16(ha1h, vbn1, aNh, 0, 0, 0);
        aNh = __builtin_amdgcn_mfma_f32_16x16x32_bf16(ha0l, vbn0, aNh, 0, 0, 0);
        aNh = __builtin_amdgcn_mfma_f32_16x16x32_bf16(ha1l, vbn1, aNh, 0, 0, 0);
        int l = lt*16 + (lane & 15);
        float br = bih[l] + bhh[l];
        float bz = bih[64+l] + bhh[64+l];
        float bn = bih[128+l];
        float cn = bhh[128+l];
        float fw0 = fcw[l*5+0], fw1 = fcw[l*5+1], fw2 = fcw[l*5+2],
              fw3 = fcw[l*5+3], fw4 = fcw[l*5+4];
        #pragma unroll
        for (int r4 = 0; r4 < 4; ++r4) {
            int rl = w*16 + (lane >> 4)*4 + r4;      // local row in block
            float rg = sigm(aR[r4] + br);
            float zg = sigm(aZ[r4] + bz);
            float ng = tanh_f(aNi[r4] + bn + rg*(aNh[r4] + cn));
            float hfv = hsh[rl][l];
            float hnv = (1.f - zg)*ng + zg*hfv;
            hnew[(size_t)(n0 + rl)*64 + l] = hnv;
            po[r4][0] += hnv*fw0; po[r4][1] += hnv*fw1; po[r4][2] += hnv*fw2;
            po[r4][3] += hnv*fw3; po[r4][4] += hnv*fw4;
        }
    }
    #pragma unroll
    for (int r4 = 0; r4 < 4; ++r4)
        #pragma unroll
        for (int j = 0; j < 5; ++j) {
            float v = po[r4][j];
            v += __shfl_xor(v, 1); v += __shfl_xor(v, 2);
            v += __shfl_xor(v, 4); v += __shfl_xor(v, 8);
            po[r4][j] = v;
        }
    if ((lane & 15) == 0) {
        #pragma unroll
        for (int r4 = 0; r4 < 4; ++r4) {
            int node = n0 + w*16 + (lane >> 4)*4 + r4;
            #pragma unroll
            for (int j = 0; j < 5; ++j) out[(size_t)node*5 + j] = po[r4][j] + fcb[j];
        }
    }
}

extern "C" void kernel_launch(void* const* d_in, const int* in_sizes, int n_in,
                              void* d_out, int out_size, void* d_ws, size_t ws_size,
                              hipStream_t stream) {
    const float* x   = (const float*)d_in[0];
    const float* ew  = (const float*)d_in[1];
    const float* h   = (const float*)d_in[2];
    const float* W1  = (const float*)d_in[3];
    const float* b1  = (const float*)d_in[4];
    const float* W2  = (const float*)d_in[5];
    const float* b2  = (const float*)d_in[6];
    const float* wih = (const float*)d_in[7];
    const float* whh = (const float*)d_in[8];
    const float* bih = (const float*)d_in[9];
    const float* bhh = (const float*)d_in[10];
    const float* fcw = (const float*)d_in[11];
    const float* fcb = (const float*)d_in[12];
    const int*   ei  = (const int*)d_in[13];
    const int* src = ei;
    const int* dst = ei + EE;

    // ws: A2p @0 (25.6MB) | epack @25.6M (9.6MB) | wpack @35.2M (48KB) | pk @36M (1.6MB)
    //     | rank @38M (4.8MB) | off @43M | bsum @44M | dinv @45M | sagg @46M
    u32*   A2p   = (u32*)d_ws;
    uint2* epack = (uint2*)((char*)d_ws + 25600000);
    uint4* wpack = (uint4*)((char*)d_ws + 35200000);
    u64*   pk    = (u64*)((char*)d_ws + 36000000);
    u32*   rank  = (u32*)((char*)d_ws + 38000000);
    int*   off   = (int*)((char*)d_ws + 43000000);    // NTOT+1
    int*   bsum  = (int*)((char*)d_ws + 44000000);    // 782
    float* dinv  = (float*)((char*)d_ws + 45000000);
    float* sagg  = (float*)((char*)d_ws + 46000000);
    float* out  = (float*)d_out;
    float* B2   = out + (size_t)NTOT*5;               // d_out tail: y2 buffer, finally hnew

    hipMemsetAsync(pk, 0, (size_t)NTOT*8, stream);
    k_degcnt<<<4688,  256, 0, stream>>>(ew, dst, pk, rank);
    k_scan1 <<<782,   256, 0, stream>>>(pk, off, bsum, dinv);
    k_scan2 <<<1,    1024, 0, stream>>>(bsum);
    k_scan3 <<<782,   256, 0, stream>>>(off, bsum);
    k_fill  <<<4688,  256, 0, stream>>>(src, dst, ew, dinv, off, rank, epack);
    k_sagg  <<<782,   256, 0, stream>>>(off, epack, x, dinv, sagg);
    k_wprep <<<12,    256, 0, stream>>>(wih, whh, wpack);
    k_l12   <<<3125,  256, 0, stream>>>(sagg, W1, b1, W2, A2p);
    k_gather<<<50000, 256, 0, stream>>>(A2p, epack, off, dinv, b2, B2);
    k_gru   <<<3125,  256, 0, stream>>>(B2, h, wpack, bih, bhh, fcw, fcb, out, B2);
}

// Round 18
// 258.059 us; speedup vs baseline: 1.4984x; 1.0354x over previous
//
#include <hip/hip_runtime.h>

#define NTOT 200000
#define EE   1200000

typedef unsigned int u32;
typedef unsigned long long u64;
typedef __attribute__((ext_vector_type(8))) short short8v;
typedef __attribute__((ext_vector_type(4))) float f32x4;

__device__ __forceinline__ float rcpf(float x) { return __builtin_amdgcn_rcpf(x); }
__device__ __forceinline__ float sigm(float x) { return rcpf(1.f + __expf(-x)); }
__device__ __forceinline__ float tanh_f(float x) { return 1.f - 2.f * rcpf(__expf(2.f * x) + 1.f); }
__device__ __forceinline__ u32 f2bf(float f) {           // RNE f32->bf16
    u32 u = __float_as_uint(f);
    return (u + 0x7fffu + ((u >> 16) & 1u)) >> 16;
}
__device__ __forceinline__ float bf2f(u32 b) { return __uint_as_float(b << 16); }
__device__ __forceinline__ float bf_lo(u32 p) { return __uint_as_float(p << 16); }
__device__ __forceinline__ float bf_hi(u32 p) { return __uint_as_float(p & 0xffff0000u); }

__device__ __forceinline__ short8v packhi8(const float* v) {
    union { u32 u[4]; short8v s; } r;
    r.u[0] = f2bf(v[0]) | (f2bf(v[1]) << 16);
    r.u[1] = f2bf(v[2]) | (f2bf(v[3]) << 16);
    r.u[2] = f2bf(v[4]) | (f2bf(v[5]) << 16);
    r.u[3] = f2bf(v[6]) | (f2bf(v[7]) << 16);
    return r.s;
}
__device__ __forceinline__ short8v packlo8(const float* v) {
    float q[8];
    #pragma unroll
    for (int i = 0; i < 8; ++i) q[i] = v[i] - bf2f(f2bf(v[i]));
    union { u32 u[4]; short8v s; } r;
    r.u[0] = f2bf(q[0]) | (f2bf(q[1]) << 16);
    r.u[1] = f2bf(q[2]) | (f2bf(q[3]) << 16);
    r.u[2] = f2bf(q[4]) | (f2bf(q[5]) << 16);
    r.u[3] = f2bf(q[6]) | (f2bf(q[7]) << 16);
    return r.s;
}

// ---------- degree+count in ONE u64 atomic; rank captured from the returned old value ----------
__global__ __launch_bounds__(256) void k_degcnt(const float* __restrict__ ew,
                                                const int* __restrict__ dst,
                                                u64* __restrict__ pk,
                                                u32* __restrict__ rank) {
    int e = blockIdx.x*256 + threadIdx.x;
    if (e < EE) {
        u64 v = (1ull << 40) | (u64)(u32)__float2uint_rn(ew[e] * 16777216.f);
        u64 old = atomicAdd(&pk[dst[e]], v);
        rank[e] = (u32)(old >> 40);          // # earlier edges with same dst
    }
}

// scan of counts (from pk) + dinv = rsqrt(1 + fixsum*2^-24) fused
__global__ __launch_bounds__(256) void k_scan1(const u64* __restrict__ pk,
                                               int* __restrict__ off,
                                               int* __restrict__ bsum,
                                               float* __restrict__ dinv) {
    __shared__ int s[256];
    int t = threadIdx.x, i = blockIdx.x*256 + t;
    int v = 0;
    if (i < NTOT) {
        u64 p = pk[i];
        v = (int)(p >> 40);
        dinv[i] = rsqrtf(1.0f + (float)(p & 0xFFFFFFFFFFull) * 5.9604644775390625e-8f);
    }
    s[t] = v; __syncthreads();
    #pragma unroll
    for (int o = 1; o < 256; o <<= 1) {
        int a = (t >= o) ? s[t-o] : 0; __syncthreads();
        s[t] += a; __syncthreads();
    }
    if (i < NTOT) off[i] = s[t] - v;
    if (t == 255) bsum[blockIdx.x] = s[255];
}

__global__ __launch_bounds__(1024) void k_scan2(int* bsum) {   // 782 totals
    __shared__ int s[1024];
    int t = threadIdx.x;
    int v = (t < 782) ? bsum[t] : 0;
    s[t] = v; __syncthreads();
    for (int o = 1; o < 1024; o <<= 1) {
        int a = (t >= o) ? s[t-o] : 0; __syncthreads();
        s[t] += a; __syncthreads();
    }
    if (t < 782) bsum[t] = s[t] - v;
}

__global__ __launch_bounds__(256) void k_scan3(int* __restrict__ off,
                                               const int* __restrict__ bsum) {
    int i = blockIdx.x*256 + threadIdx.x;
    if (i < NTOT) off[i] = off[i] + bsum[blockIdx.x];
    if (i == 0) off[NTOT] = EE;
}

// fill CSR slots with precomputed {src, norm} — NO atomics: slot = off[dst] + rank
__global__ __launch_bounds__(256) void k_fill(const int* __restrict__ src,
                                              const int* __restrict__ dst,
                                              const float* __restrict__ ew,
                                              const float* __restrict__ dinv,
                                              const int* __restrict__ off,
                                              const u32* __restrict__ rank,
                                              uint2* __restrict__ epack) {
    int e = blockIdx.x*256 + threadIdx.x;
    if (e >= EE) return;
    int d = dst[e], s = src[e];
    float norm = dinv[s] * ew[e] * dinv[d];
    int p = off[d] + (int)rank[e];
    epack[p] = make_uint2((u32)s, __float_as_uint(norm));
}

// layer-1 scalar aggregation (T=1 rank-1 trick)
__global__ __launch_bounds__(256) void k_sagg(const int* __restrict__ off,
                                              const uint2* __restrict__ epack,
                                              const float* __restrict__ x,
                                              const float* __restrict__ dinv,
                                              float* __restrict__ sagg) {
    int n = blockIdx.x*256 + threadIdx.x;
    if (n >= NTOT) return;
    int e0 = off[n], e1 = off[n+1];
    float s = 0.f;
    for (int e = e0; e < e1; ++e) {
        uint2 ep = epack[e];
        s += __uint_as_float(ep.y) * x[ep.x];
    }
    float di = dinv[n];
    sagg[n] = s + di*di*x[n];
}

// pack wih/whh into MFMA B-frag-linear bf16: tile tau (0..23 ih, 24..47 hh)
__global__ __launch_bounds__(256) void k_wprep(const float* __restrict__ wih,
                                               const float* __restrict__ whh,
                                               uint4* __restrict__ wpack) {
    int v = blockIdx.x*256 + threadIdx.x;
    if (v >= 3072) return;
    int lane = v & 63, tau = v >> 6;
    const float* W = (tau < 24) ? wih : whh;
    int tt = tau % 24;
    int lt = tt >> 1, ks = tt & 1;
    const float* s = W + (lt*16 + (lane & 15))*64 + ks*32 + (lane >> 4)*8;
    uint4 o;
    o.x = f2bf(s[0]) | (f2bf(s[1]) << 16);
    o.y = f2bf(s[2]) | (f2bf(s[3]) << 16);
    o.z = f2bf(s[4]) | (f2bf(s[5]) << 16);
    o.w = f2bf(s[6]) | (f2bf(s[7]) << 16);
    wpack[v] = o;
}

// fused: y1 = relu(sagg*W1 + b1)  ->  A2 = y1 @ W2, stored packed bf16 (128B/row)
__global__ __launch_bounds__(256) void k_l12(const float* __restrict__ sagg,
                                             const float* __restrict__ W1,
                                             const float* __restrict__ b1,
                                             const float* __restrict__ W2,
                                             u32* __restrict__ A2p) {
    __shared__ float ysh[64][68];
    __shared__ float wsh[64*68];              // W2 row k at k*68, f32
    int t = threadIdx.x;
    int n0 = blockIdx.x * 64;
    #pragma unroll
    for (int i = 0; i < 16; ++i) {
        int v = t + i*256;                    // coalesced global read of W2
        wsh[(v >> 6)*68 + (v & 63)] = W2[v];
    }
    {
        int row = t >> 2, c0 = (t & 3) * 16;
        float sv = sagg[n0 + row];
        #pragma unroll
        for (int q = 0; q < 4; ++q) {
            float4 w  = *(const float4*)(W1 + c0 + q*4);
            float4 bb = *(const float4*)(b1 + c0 + q*4);
            ysh[row][c0+q*4+0] = fmaxf(sv*w.x + bb.x, 0.f);
            ysh[row][c0+q*4+1] = fmaxf(sv*w.y + bb.y, 0.f);
            ysh[row][c0+q*4+2] = fmaxf(sv*w.z + bb.z, 0.f);
            ysh[row][c0+q*4+3] = fmaxf(sv*w.w + bb.w, 0.f);
        }
    }
    __syncthreads();
    int p = t >> 3, c = t & 7;
    float acc0[8], acc1[8];
    #pragma unroll
    for (int j = 0; j < 8; ++j) { acc0[j] = 0.f; acc1[j] = 0.f; }
    #pragma unroll 4
    for (int k = 0; k < 64; ++k) {
        float y0 = ysh[p][k], y1 = ysh[p+32][k];
        const float* wr = wsh + k*68 + c*8;
        float4 w0 = *(const float4*)wr;
        float4 w1 = *(const float4*)(wr + 4);
        acc0[0] += y0*w0.x; acc0[1] += y0*w0.y; acc0[2] += y0*w0.z; acc0[3] += y0*w0.w;
        acc0[4] += y0*w1.x; acc0[5] += y0*w1.y; acc0[6] += y0*w1.z; acc0[7] += y0*w1.w;
        acc1[0] += y1*w0.x; acc1[1] += y1*w0.y; acc1[2] += y1*w0.z; acc1[3] += y1*w0.w;
        acc1[4] += y1*w1.x; acc1[5] += y1*w1.y; acc1[6] += y1*w1.z; acc1[7] += y1*w1.w;
    }
    int na = n0 + p, nb = n0 + p + 32;
    uint4 pk;
    pk.x = f2bf(acc0[0]) | (f2bf(acc0[1]) << 16);
    pk.y = f2bf(acc0[2]) | (f2bf(acc0[3]) << 16);
    pk.z = f2bf(acc0[4]) | (f2bf(acc0[5]) << 16);
    pk.w = f2bf(acc0[6]) | (f2bf(acc0[7]) << 16);
    *(uint4*)(A2p + (size_t)na*32 + c*4) = pk;
    pk.x = f2bf(acc1[0]) | (f2bf(acc1[1]) << 16);
    pk.y = f2bf(acc1[2]) | (f2bf(acc1[3]) << 16);
    pk.z = f2bf(acc1[4]) | (f2bf(acc1[5]) << 16);
    pk.w = f2bf(acc1[6]) | (f2bf(acc1[7]) << 16);
    *(uint4*)(A2p + (size_t)nb*32 + c*4) = pk;
}

// CSR gather, 8-edge ILP (2x unroll), bf16 rows — wave per node, 200K waves of TLP
__global__ __launch_bounds__(256) void k_gather(const u32* __restrict__ A2p,
                                                const uint2* __restrict__ epack,
                                                const int* __restrict__ off,
                                                const float* __restrict__ dinv,
                                                const float* __restrict__ b2,
                                                float* __restrict__ B2) {
    int wv = (blockIdx.x*256 + threadIdx.x) >> 6;
    int lane = threadIdx.x & 63;
    if (wv >= NTOT) return;
    int g = lane >> 4, q = lane & 15;
    int e0 = off[wv], e1 = off[wv+1];
    float ax = 0.f, ay = 0.f, az = 0.f, aw = 0.f;
    for (int e = e0 + g; e < e1; e += 8) {
        uint2 ep0 = epack[e];
        // second edge: zero-norm dummy when past end (0 * finite == exact 0)
        uint2 ep1 = (e + 4 < e1) ? epack[e + 4] : make_uint2(0u, 0u);
        float n0 = __uint_as_float(ep0.y);
        float n1 = __uint_as_float(ep1.y);
        uint2 pw0 = *(const uint2*)(A2p + (size_t)ep0.x*32 + q*2);
        uint2 pw1 = *(const uint2*)(A2p + (size_t)ep1.x*32 + q*2);
        ax += n0*bf_lo(pw0.x); ay += n0*bf_hi(pw0.x);
        az += n0*bf_lo(pw0.y); aw += n0*bf_hi(pw0.y);
        ax += n1*bf_lo(pw1.x); ay += n1*bf_hi(pw1.x);
        az += n1*bf_lo(pw1.y); aw += n1*bf_hi(pw1.y);
    }
    ax += __shfl_xor(ax, 16); ax += __shfl_xor(ax, 32);
    ay += __shfl_xor(ay, 16); ay += __shfl_xor(ay, 32);
    az += __shfl_xor(az, 16); az += __shfl_xor(az, 32);
    aw += __shfl_xor(aw, 16); aw += __shfl_xor(aw, 32);
    if (g == 0) {
        float di = dinv[wv], d2 = di*di;
        uint2 pw = *(const uint2*)(A2p + (size_t)wv*32 + q*2);
        float4 bb = *(const float4*)(b2 + q*4);
        float4 o;
        o.x = fmaxf(ax + d2*bf_lo(pw.x) + bb.x, 0.f);
        o.y = fmaxf(ay + d2*bf_hi(pw.x) + bb.y, 0.f);
        o.z = fmaxf(az + d2*bf_lo(pw.y) + bb.z, 0.f);
        o.w = fmaxf(aw + d2*bf_hi(pw.y) + bb.w, 0.f);
        *(float4*)(B2 + (size_t)wv*64 + q*4) = o;
    }
}

// ---------- MFMA GRU + FC head, LDS-staged (round-16 proven) ----------
__global__ __launch_bounds__(256) void k_gru(const float* B2,
                                             const float* __restrict__ h_in,
                                             const uint4* __restrict__ wpack,
                                             const float* __restrict__ bih,
                                             const float* __restrict__ bhh,
                                             const float* __restrict__ fcw,
                                             const float* __restrict__ fcb,
                                             float* __restrict__ out,
                                             float* hnew) {
    __shared__ float ysh[64][68];             // pad 68: b128 row-strided reads = 2-way (free)
    __shared__ float hsh[64][68];
    int t = threadIdx.x;
    int lane = t & 63, w = t >> 6;
    int n0 = blockIdx.x * 64;
    {   // coalesced staging of B2 and h tiles
        int r = t >> 2, qq = t & 3;
        const float4* bp = (const float4*)(B2 + (size_t)(n0 + r)*64 + qq*16);
        const float4* hp = (const float4*)(h_in + (size_t)(n0 + r)*64 + qq*16);
        float4* dy = (float4*)&ysh[r][qq*16];
        float4* dh = (float4*)&hsh[r][qq*16];
        dy[0] = bp[0]; dy[1] = bp[1]; dy[2] = bp[2]; dy[3] = bp[3];
        dh[0] = hp[0]; dh[1] = hp[1]; dh[2] = hp[2]; dh[3] = hp[3];
    }
    __syncthreads();
    int rowL = w*16 + (lane & 15);
    int kb = (lane >> 4) * 8;
    float yf[16], hb[16];
    *(float4*)&yf[0]  = *(const float4*)&ysh[rowL][kb];
    *(float4*)&yf[4]  = *(const float4*)&ysh[rowL][kb+4];
    *(float4*)&yf[8]  = *(const float4*)&ysh[rowL][kb+32];
    *(float4*)&yf[12] = *(const float4*)&ysh[rowL][kb+36];
    *(float4*)&hb[0]  = *(const float4*)&hsh[rowL][kb];
    *(float4*)&hb[4]  = *(const float4*)&hsh[rowL][kb+4];
    *(float4*)&hb[8]  = *(const float4*)&hsh[rowL][kb+32];
    *(float4*)&hb[12] = *(const float4*)&hsh[rowL][kb+36];
    short8v ya0h = packhi8(&yf[0]), ya1h = packhi8(&yf[8]);
    short8v ya0l = packlo8(&yf[0]), ya1l = packlo8(&yf[8]);
    short8v ha0h = packhi8(&hb[0]), ha1h = packhi8(&hb[8]);
    short8v ha0l = packlo8(&hb[0]), ha1l = packlo8(&hb[8]);
    float po[4][5] = {};
    #pragma unroll
    for (int lt = 0; lt < 4; ++lt) {
        short8v wbr0 = *(const short8v*)&wpack[(lt*2+0)*64 + lane];
        short8v wbr1 = *(const short8v*)&wpack[(lt*2+1)*64 + lane];
        short8v wbz0 = *(const short8v*)&wpack[((lt+4)*2+0)*64 + lane];
        short8v wbz1 = *(const short8v*)&wpack[((lt+4)*2+1)*64 + lane];
        short8v wbn0 = *(const short8v*)&wpack[((lt+8)*2+0)*64 + lane];
        short8v wbn1 = *(const short8v*)&wpack[((lt+8)*2+1)*64 + lane];
        short8v vbr0 = *(const short8v*)&wpack[1536 + (lt*2+0)*64 + lane];
        short8v vbr1 = *(const short8v*)&wpack[1536 + (lt*2+1)*64 + lane];
        short8v vbz0 = *(const short8v*)&wpack[1536 + ((lt+4)*2+0)*64 + lane];
        short8v vbz1 = *(const short8v*)&wpack[1536 + ((lt+4)*2+1)*64 + lane];
        short8v vbn0 = *(const short8v*)&wpack[1536 + ((lt+8)*2+0)*64 + lane];
        short8v vbn1 = *(const short8v*)&wpack[1536 + ((lt+8)*2+1)*64 + lane];
        f32x4 aR  = {0.f,0.f,0.f,0.f};
        f32x4 aZ  = {0.f,0.f,0.f,0.f};
        f32x4 aNi = {0.f,0.f,0.f,0.f};
        f32x4 aNh = {0.f,0.f,0.f,0.f};
        aR = __builtin_amdgcn_mfma_f32_16x16x32_bf16(ya0h, wbr0, aR, 0, 0, 0);
        aR = __builtin_amdgcn_mfma_f32_16x16x32_bf16(ya1h, wbr1, aR, 0, 0, 0);
        aR = __builtin_amdgcn_mfma_f32_16x16x32_bf16(ya0l, wbr0, aR, 0, 0, 0);
        aR = __builtin_amdgcn_mfma_f32_16x16x32_bf16(ya1l, wbr1, aR, 0, 0, 0);
        aR = __builtin_amdgcn_mfma_f32_16x16x32_bf16(ha0h, vbr0, aR, 0, 0, 0);
        aR = __builtin_amdgcn_mfma_f32_16x16x32_bf16(ha1h, vbr1, aR, 0, 0, 0);
        aR = __builtin_amdgcn_mfma_f32_16x16x32_bf16(ha0l, vbr0, aR, 0, 0, 0);
        aR = __builtin_amdgcn_mfma_f32_16x16x32_bf16(ha1l, vbr1, aR, 0, 0, 0);
        aZ = __builtin_amdgcn_mfma_f32_16x16x32_bf16(ya0h, wbz0, aZ, 0, 0, 0);
        aZ = __builtin_amdgcn_mfma_f32_16x16x32_bf16(ya1h, wbz1, aZ, 0, 0, 0);
        aZ = __builtin_amdgcn_mfma_f32_16x16x32_bf16(ya0l, wbz0, aZ, 0, 0, 0);
        aZ = __builtin_amdgcn_mfma_f32_16x16x32_bf16(ya1l, wbz1, aZ, 0, 0, 0);
        aZ = __builtin_amdgcn_mfma_f32_16x16x32_bf16(ha0h, vbz0, aZ, 0, 0, 0);
        aZ = __builtin_amdgcn_mfma_f32_16x16x32_bf16(ha1h, vbz1, aZ, 0, 0, 0);
        aZ = __builtin_amdgcn_mfma_f32_16x16x32_bf16(ha0l, vbz0, aZ, 0, 0, 0);
        aZ = __builtin_amdgcn_mfma_f32_16x16x32_bf16(ha1l, vbz1, aZ, 0, 0, 0);
        aNi = __builtin_amdgcn_mfma_f32_16x16x32_bf16(ya0h, wbn0, aNi, 0, 0, 0);
        aNi = __builtin_amdgcn_mfma_f32_16x16x32_bf16(ya1h, wbn1, aNi, 0, 0, 0);
        aNi = __builtin_amdgcn_mfma_f32_16x16x32_bf16(ya0l, wbn0, aNi, 0, 0, 0);
        aNi = __builtin_amdgcn_mfma_f32_16x16x32_bf16(ya1l, wbn1, aNi, 0, 0, 0);
        aNh = __builtin_amdgcn_mfma_f32_16x16x32_bf16(ha0h, vbn0, aNh, 0, 0, 0);
        aNh = __builtin_amdgcn_mfma_f32_16x16x32_bf16(ha1h, vbn1, aNh, 0, 0, 0);
        aNh = __builtin_amdgcn_mfma_f32_16x16x32_bf16(ha0l, vbn0, aNh, 0, 0, 0);
        aNh = __builtin_amdgcn_mfma_f32_16x16x32_bf16(ha1l, vbn1, aNh, 0, 0, 0);
        int l = lt*16 + (lane & 15);
        float br = bih[l] + bhh[l];
        float bz = bih[64+l] + bhh[64+l];
        float bn = bih[128+l];
        float cn = bhh[128+l];
        float fw0 = fcw[l*5+0], fw1 = fcw[l*5+1], fw2 = fcw[l*5+2],
              fw3 = fcw[l*5+3], fw4 = fcw[l*5+4];
        #pragma unroll
        for (int r4 = 0; r4 < 4; ++r4) {
            int rl = w*16 + (lane >> 4)*4 + r4;      // local row in block
            float rg = sigm(aR[r4] + br);
            float zg = sigm(aZ[r4] + bz);
            float ng = tanh_f(aNi[r4] + bn + rg*(aNh[r4] + cn));
            float hfv = hsh[rl][l];
            float hnv = (1.f - zg)*ng + zg*hfv;
            hnew[(size_t)(n0 + rl)*64 + l] = hnv;
            po[r4][0] += hnv*fw0; po[r4][1] += hnv*fw1; po[r4][2] += hnv*fw2;
            po[r4][3] += hnv*fw3; po[r4][4] += hnv*fw4;
        }
    }
    #pragma unroll
    for (int r4 = 0; r4 < 4; ++r4)
        #pragma unroll
        for (int j = 0; j < 5; ++j) {
            float v = po[r4][j];
            v += __shfl_xor(v, 1); v += __shfl_xor(v, 2);
            v += __shfl_xor(v, 4); v += __shfl_xor(v, 8);
            po[r4][j] = v;
        }
    if ((lane & 15) == 0) {
        #pragma unroll
        for (int r4 = 0; r4 < 4; ++r4) {
            int node = n0 + w*16 + (lane >> 4)*4 + r4;
            #pragma unroll
            for (int j = 0; j < 5; ++j) out[(size_t)node*5 + j] = po[r4][j] + fcb[j];
        }
    }
}

extern "C" void kernel_launch(void* const* d_in, const int* in_sizes, int n_in,
                              void* d_out, int out_size, void* d_ws, size_t ws_size,
                              hipStream_t stream) {
    const float* x   = (const float*)d_in[0];
    const float* ew  = (const float*)d_in[1];
    const float* h   = (const float*)d_in[2];
    const float* W1  = (const float*)d_in[3];
    const float* b1  = (const float*)d_in[4];
    const float* W2  = (const float*)d_in[5];
    const float* b2  = (const float*)d_in[6];
    const float* wih = (const float*)d_in[7];
    const float* whh = (const float*)d_in[8];
    const float* bih = (const float*)d_in[9];
    const float* bhh = (const float*)d_in[10];
    const float* fcw = (const float*)d_in[11];
    const float* fcb = (const float*)d_in[12];
    const int*   ei  = (const int*)d_in[13];
    const int* src = ei;
    const int* dst = ei + EE;

    // ws: A2p @0 (25.6MB) | epack @25.6M (9.6MB) | wpack @35.2M (48KB) | pk @36M (1.6MB)
    //     | rank @38M (4.8MB) | off @43M | bsum @44M | dinv @45M | sagg @46M
    u32*   A2p   = (u32*)d_ws;
    uint2* epack = (uint2*)((char*)d_ws + 25600000);
    uint4* wpack = (uint4*)((char*)d_ws + 35200000);
    u64*   pk    = (u64*)((char*)d_ws + 36000000);
    u32*   rank  = (u32*)((char*)d_ws + 38000000);
    int*   off   = (int*)((char*)d_ws + 43000000);    // NTOT+1
    int*   bsum  = (int*)((char*)d_ws + 44000000);    // 782
    float* dinv  = (float*)((char*)d_ws + 45000000);
    float* sagg  = (float*)((char*)d_ws + 46000000);
    float* out  = (float*)d_out;
    float* B2   = out + (size_t)NTOT*5;               // d_out tail: y2 buffer, finally hnew

    hipMemsetAsync(pk, 0, (size_t)NTOT*8, stream);
    k_degcnt<<<4688,  256, 0, stream>>>(ew, dst, pk, rank);
    k_scan1 <<<782,   256, 0, stream>>>(pk, off, bsum, dinv);
    k_scan2 <<<1,    1024, 0, stream>>>(bsum);
    k_scan3 <<<782,   256, 0, stream>>>(off, bsum);
    k_fill  <<<4688,  256, 0, stream>>>(src, dst, ew, dinv, off, rank, epack);
    k_sagg  <<<782,   256, 0, stream>>>(off, epack, x, dinv, sagg);
    k_wprep <<<12,    256, 0, stream>>>(wih, whh, wpack);
    k_l12   <<<3125,  256, 0, stream>>>(sagg, W1, b1, W2, A2p);
    k_gather<<<50000, 256, 0, stream>>>(A2p, epack, off, dinv, b2, B2);
    k_gru   <<<3125,  256, 0, stream>>>(B2, h, wpack, bih, bhh, fcw, fcb, out, B2);
}